// Round 1
// 435.129 us; speedup vs baseline: 1.3374x; 1.3374x over previous
//
#include <hip/hip_runtime.h>
#include <stdint.h>

#define N_PTS 1000000
#define FIN   64
#define HID   32
#define GB    2
#define GX    512
#define GY    512
#define GZ    64
#define KMAX  128
#define NBUCKET 4096
#define BITS_LO 0x3E4CCCCDu   /* bits of 0.2f */
#define BUCKET_SHIFT 13
#define CAND_CAP 4096

/* ---- workspace layout (identical footprint to R3: known to fit) ----
 * [bitmap 4 MB | hist 16 KB | counters 64 B | pad | grid 134 MB (UNCLEARED) | keys 8 MB | cand 32 KB]
 * Grid is never memset: a cell is only read if its bitmap bit is set, which
 * implies a signed atomicMax with a positive value already happened; the
 * 0xAA ws poison is negative int32 and loses automatically.
 * keys is now a PER-POINT slot array (keys[i], 0 = not a peak): k_peak has
 * NO ordering atomic at all. The previous wave-aggregated atomicAdd on
 * counters[0] was ~15.6k serialized device-scope same-address RMWs
 * (~12 ns each ≈ the entire 185 us of k_peak).
 */
#define BM_WORDS   (GB*GX*GY)
#define BM_BYTES   ((size_t)BM_WORDS*8)
#define HIST_OFF   BM_BYTES
#define HIST_BYTES (NBUCKET*4)
#define CNT_OFF    (HIST_OFF + HIST_BYTES)
#define CNT_BYTES  64
#define CLEAR_BYTES (CNT_OFF + CNT_BYTES)
#define GRID_OFF   ((size_t)4214784)
#define GRID_CELLS ((size_t)GB*GX*GY*GZ)
#define GRID_BYTES (GRID_CELLS*4)
#define KEYS_OFF   (GRID_OFF + GRID_BYTES)
#define CAND_OFF   (KEYS_OFF + (size_t)N_PTS*8)

/* counters: [1]=collect count C (counters[0] no longer used) */

__global__ __launch_bounds__(256) void k_mlp(
    const float* __restrict__ feats,
    const int* __restrict__ cb, const int* __restrict__ cx,
    const int* __restrict__ cy, const int* __restrict__ cz,
    const int* __restrict__ mask_i,
    const float* __restrict__ W1, const float* __restrict__ b1,
    const float* __restrict__ W2, const float* __restrict__ b2,
    float* __restrict__ score_out, int* __restrict__ grid,
    unsigned long long* __restrict__ bm)
{
    /* per-block mask-format detection: int32-read of byte-packed bools shows
       values >1 with overwhelming probability over 256 words; true int32
       0/1 data never does. Same 1 KB read by every block -> L2 broadcast. */
    __shared__ unsigned int s_mflag;
    if (threadIdx.x == 0) s_mflag = 0u;
    __syncthreads();
    {
        unsigned int v = (unsigned int)mask_i[threadIdx.x];
        if (v > 1u) atomicOr(&s_mflag, 1u);
    }
    __syncthreads();
    bool mask_is_bytes = (s_mflag != 0u);

    int i = blockIdx.x * 256 + threadIdx.x;
    if (i >= N_PTS) return;

    bool mk = mask_is_bytes ? (((const unsigned char*)mask_i)[i] != 0)
                            : (mask_i[i] != 0);

    float s = 0.0f;
    if (mk) {
        float hj[HID];
#pragma unroll
        for (int j = 0; j < HID; ++j) hj[j] = b1[j];

        const float4* rp = (const float4*)(feats + (size_t)i * FIN);
#pragma unroll 4
        for (int q = 0; q < FIN / 4; ++q) {
            float4 v = rp[q];
            const float* w0 = W1 + (4*q + 0) * HID;
            const float* w1 = W1 + (4*q + 1) * HID;
            const float* w2 = W1 + (4*q + 2) * HID;
            const float* w3 = W1 + (4*q + 3) * HID;
#pragma unroll
            for (int j = 0; j < HID; ++j) {
                float acc = hj[j];
                acc = fmaf(v.x, w0[j], acc);
                acc = fmaf(v.y, w1[j], acc);
                acc = fmaf(v.z, w2[j], acc);
                acc = fmaf(v.w, w3[j], acc);
                hj[j] = acc;
            }
        }

        float x = b2[0];
#pragma unroll
        for (int j = 0; j < HID; ++j) x += fmaxf(hj[j], 0.0f) * W2[j];

        s = 1.0f / (1.0f + expf(-x));
    }

    score_out[i] = s;

    if (s > 0.1f) {
        int sb = (int)__float_as_uint(s);   /* positive float bits */
        int b = cb[i], xx = cx[i], yy = cy[i], zz = cz[i];
        int col = (b*GX + xx)*GY + yy;
        atomicOr(&bm[col], 1ull << zz);          /* scattered: ok */
        atomicMax(&grid[((size_t)col << 6) + (size_t)zz], sb);
    }
}

__global__ __launch_bounds__(256) void k_peak(
    const float* __restrict__ s_buf,
    const int* __restrict__ cb, const int* __restrict__ cx,
    const int* __restrict__ cy, const int* __restrict__ cz,
    const int* __restrict__ grid,
    const unsigned long long* __restrict__ bm,
    unsigned long long* __restrict__ keys,
    unsigned int* __restrict__ hist)
{
    int i = blockIdx.x * 256 + threadIdx.x;
    if (i >= N_PTS) return;
    float s = s_buf[i];
    bool cand = (s > 0.2f);

    int  sb = (int)__float_as_uint(s);
    bool peak = false;
    unsigned int bucket = 0;

    if (cand) {
        int b = cb[i], x = cx[i], y = cy[i], z = cz[i];
        int z0 = (z > 0) ? z - 1 : 0;
        int z1 = (z < GZ-1) ? z + 1 : GZ-1;
        unsigned wmask = (1u << (z1 - z0 + 1)) - 1u;

        int xm = (x > 0) ? x - 1 : 0;
        int xp = (x < GX-1) ? x + 1 : GX-1;
        int ym = (y > 0) ? y - 1 : 0;
        int yp = (y < GY-1) ? y + 1 : GY-1;
        int rb = b * GX;
        int c0 = (rb + xm) * GY, c1 = (rb + x) * GY, c2 = (rb + xp) * GY;
        int col0 = c0+ym, col1 = c0+y, col2 = c0+yp;
        int col3 = c1+ym, col4 = c1+y, col5 = c1+yp;
        int col6 = c2+ym, col7 = c2+y, col8 = c2+yp;

        unsigned long long w0 = bm[col0], w1 = bm[col1], w2 = bm[col2];
        unsigned long long w3 = bm[col3], w4 = bm[col4], w5 = bm[col5];
        unsigned long long w6 = bm[col6], w7 = bm[col7], w8 = bm[col8];

        /* no early exit: the 9 column loops are mutually independent so the
           scattered grid loads can be in flight simultaneously */
        int vmax = (int)0x80000000;
#define CHK(WV, CL) do { \
            unsigned win = (unsigned)((WV) >> z0) & wmask; \
            while (win) { \
                int t = __ffs(win) - 1; win &= win - 1u; \
                int v = grid[((size_t)(CL) << 6) + (size_t)(z0 + t)]; \
                vmax = (v > vmax) ? v : vmax; \
            } \
        } while (0)
        CHK(w0, col0); CHK(w1, col1); CHK(w2, col2);
        CHK(w3, col3); CHK(w4, col4); CHK(w5, col5);
        CHK(w6, col6); CHK(w7, col7); CHK(w8, col8);
#undef CHK
        peak = (vmax <= sb);
        bucket = ((unsigned int)sb - BITS_LO) >> BUCKET_SHIFT;
        if (bucket > NBUCKET - 1u) bucket = NBUCKET - 1u;
    }

    /* direct-indexed key slot: NO ordering atomic, no cross-wave dependency.
       Coalesced 8 B/thread store; 0 marks "not a peak" (a real peak always
       has sb bits > 0x3E4CCCCD so the high word is nonzero). */
    unsigned long long kv = 0ull;
    if (peak) {
        kv = ((unsigned long long)(unsigned int)sb << 32) | (unsigned int)(~(unsigned int)i);
        atomicAdd(&hist[bucket], 1u);   /* scattered over 4096 buckets: ok */
    }
    keys[i] = kv;
}

/* fused cutoff+collect: every block redundantly computes the cutoff bucket
 * from hist (16 KB, L2-hot), then grid-strides the FULL per-point keys array
 * (8 MB coalesced read) compacting only above-cutoff entries (~a few hundred
 * total -> counters[1] atomic traffic is negligible). */
__global__ __launch_bounds__(256) void k_collect(
    const unsigned long long* __restrict__ keys,
    unsigned long long* __restrict__ cand,
    unsigned int* __restrict__ counters,
    const unsigned int* __restrict__ hist)
{
    __shared__ unsigned int lh[NBUCKET];
    __shared__ unsigned int csum[256];
    __shared__ unsigned int s_cut;
    int t = threadIdx.x;
    if (t == 0) s_cut = 0u;
    unsigned int ssum = 0;
    for (int k = 0; k < NBUCKET/256; ++k) {
        unsigned int v = hist[t*(NBUCKET/256) + k];
        lh[t*(NBUCKET/256) + k] = v;
        ssum += v;
    }
    csum[t] = ssum;
    __syncthreads();
    for (int off = 1; off < 256; off <<= 1) {
        unsigned int v = (t + off < 256) ? csum[t + off] : 0u;
        __syncthreads();
        csum[t] += v;
        __syncthreads();
    }
    unsigned int incl = csum[t];
    unsigned int excl = (t + 1 < 256) ? csum[t + 1] : 0u;
    if (incl >= KMAX && excl < KMAX) {
        unsigned int cum = excl;
        int cut = t * (NBUCKET/256);
        for (int b = t*(NBUCKET/256) + (NBUCKET/256) - 1; b >= t*(NBUCKET/256); --b) {
            cum += lh[b];
            if (cum >= KMAX) { cut = b; break; }
        }
        s_cut = (unsigned int)cut;
    }
    __syncthreads();
    unsigned int cut = s_cut;

    for (unsigned int i = blockIdx.x * 256 + t; i < N_PTS; i += gridDim.x * 256) {
        unsigned long long k = keys[i];
        bool take = false;
        if (k != 0ull) {
            unsigned int sbu = (unsigned int)(k >> 32);
            unsigned int bucket = (sbu - BITS_LO) >> BUCKET_SHIFT;
            if (bucket > NBUCKET - 1u) bucket = NBUCKET - 1u;
            take = (bucket >= cut);
        }
        unsigned long long bal = __ballot(take ? 1 : 0);
        if (bal) {
            int lane = threadIdx.x & 63;
            int leader = __ffsll((long long)bal) - 1;
            unsigned int base = 0;
            if (lane == leader) base = atomicAdd(&counters[1], (unsigned int)__popcll(bal));
            base = __shfl(base, leader);
            if (take) {
                unsigned int p = base + (unsigned int)__popcll(bal & ((1ull << lane) - 1ull));
                if (p < CAND_CAP) cand[p] = k;
            }
        }
    }
}

__global__ __launch_bounds__(1024) void k_final(
    const unsigned long long* __restrict__ cand,
    const unsigned int* __restrict__ counters,
    const int* __restrict__ cb, const int* __restrict__ cx,
    const int* __restrict__ cy, const int* __restrict__ cz,
    float* __restrict__ out)
{
    __shared__ unsigned long long sk[CAND_CAP];
    int t = threadIdx.x;
    unsigned int C = counters[1];
    if (C > CAND_CAP) C = CAND_CAP;
    int P = KMAX;
    while (P < (int)C) P <<= 1;
    for (int k = t; k < P; k += 1024) sk[k] = (k < (int)C) ? cand[k] : 0ull;
    __syncthreads();

    for (int k = 2; k <= P; k <<= 1) {
        for (int j = k >> 1; j > 0; j >>= 1) {
            for (int i = t; i < P; i += 1024) {
                int ixj = i ^ j;
                if (ixj > i) {
                    unsigned long long a = sk[i], b = sk[ixj];
                    bool up = ((i & k) == 0);
                    if (up ? (a < b) : (a > b)) { sk[i] = b; sk[ixj] = a; }
                }
            }
            __syncthreads();
        }
    }

    if (t < KMAX) {
        unsigned long long k = sk[t];
        float val; int idx;
        if (k != 0ull) {
            idx = (int)(~(unsigned int)(k & 0xFFFFFFFFull));
            val = __uint_as_float((unsigned int)(k >> 32));
        } else {
            idx = t;
            val = -1.0f;
        }
        out[N_PTS + t]         = (float)idx;
        out[N_PTS + KMAX + t]  = val;
        float* pc = out + N_PTS + 2*KMAX + 4*t;
        pc[0] = (float)cb[idx]; pc[1] = (float)cx[idx];
        pc[2] = (float)cy[idx]; pc[3] = (float)cz[idx];
    }
}

extern "C" void kernel_launch(void* const* d_in, const int* in_sizes, int n_in,
                              void* d_out, int out_size, void* d_ws, size_t ws_size,
                              hipStream_t stream) {
    const float* feats = (const float*)d_in[0];
    const int*   cb    = (const int*)d_in[1];
    const int*   cx    = (const int*)d_in[2];
    const int*   cy    = (const int*)d_in[3];
    const int*   cz    = (const int*)d_in[4];
    const int*   mask  = (const int*)d_in[5];
    const float* W1    = (const float*)d_in[6];
    const float* b1    = (const float*)d_in[7];
    const float* W2    = (const float*)d_in[8];
    const float* b2    = (const float*)d_in[9];
    float* out = (float*)d_out;

    char* ws = (char*)d_ws;
    unsigned long long* bm       = (unsigned long long*)(ws);
    unsigned int*       hist     = (unsigned int*)(ws + HIST_OFF);
    unsigned int*       counters = (unsigned int*)(ws + CNT_OFF);
    int*                grid     = (int*)(ws + GRID_OFF);
    unsigned long long* keys     = (unsigned long long*)(ws + KEYS_OFF);
    unsigned long long* cand     = (unsigned long long*)(ws + CAND_OFF);

    hipMemsetAsync(ws, 0, CLEAR_BYTES, stream);

    int nb = (N_PTS + 255) / 256;
    k_mlp<<<nb, 256, 0, stream>>>(feats, cb, cx, cy, cz, mask,
                                  W1, b1, W2, b2, out, grid, bm);
    k_peak<<<nb, 256, 0, stream>>>(out, cb, cx, cy, cz, grid, bm, keys, hist);
    k_collect<<<512, 256, 0, stream>>>(keys, cand, counters, hist);
    k_final<<<1, 1024, 0, stream>>>(cand, counters, cb, cx, cy, cz, out);
}